// Round 6
// baseline (376.355 us; speedup 1.0000x reference)
//
#include <hip/hip_runtime.h>

#define T_STEPS 512
#define HSTR 80        // _Float16 per h batch-row (160 B)
#define XSTRIDE 520    // _Float16 per x-row
#define OSTRIDE 513    // floats per out-row

typedef _Float16 half8v __attribute__((ext_vector_type(8)));
typedef _Float16 half4v __attribute__((ext_vector_type(4)));
typedef float f32x4 __attribute__((ext_vector_type(4)));

#define K1 1.442695041f    // log2(e)
#define K2 2.885390082f    // 2*log2(e)
#define CZCL 43.28085123f  // 15*K2, clamp in cz = cs*K2 domain

#define MFMA16(A,B,C) __builtin_amdgcn_mfma_f32_16x16x32_f16((A),(B),(C),0,0,0)
#define SGB(m,n) __builtin_amdgcn_sched_group_barrier((m),(n),0)
#define LGKM0 asm volatile("s_waitcnt lgkmcnt(0)" ::: "memory")

__device__ __forceinline__ float ex2(float x) {
#if __has_builtin(__builtin_amdgcn_exp2f)
    return __builtin_amdgcn_exp2f(x);
#else
    return exp2f(x);
#endif
}
__device__ __forceinline__ float rcp_fast(float x) {
#if __has_builtin(__builtin_amdgcn_rcpf)
    return __builtin_amdgcn_rcpf(x);
#else
    return 1.0f / x;
#endif
}

// R16: barrier-free single-wave recurrence. 256 blocks x 4 INDEPENDENT waves
// (no __syncthreads in the kernel). Each wave owns 2 batches end-to-end:
// A dup-8 (row m -> batch m>>3), 16 col-tiles (4 classes x 4 unit-groups),
// 32 MFMAs/step on a private SIMD. h exchange = per-wave LDS + lgkmcnt only.
// k-split phases: 16 a0-MFMAs (need h groups 0/1) then 16 a1-MFMAs (groups
// 2/3). Lane parity picks act unit-group: chainA = groups{0,1} (u=q&1),
// chainB = groups{2,3} (u=2+(q&1)) -> 2 chains/lane, no redundant act work.
// Cross-step pipeline: chainB(t-1) runs in phase A of t (vB precomputed),
// chainA(t) in phase B; a1 read mid-phase-A, a0 read late phase-B.
__global__ __launch_bounds__(256, 1) void lstm_kernel(
    const float* __restrict__ x, const float* __restrict__ w_ih,
    const float* __restrict__ w_hh, const float* __restrict__ b_ih,
    const float* __restrict__ b_hh, const float* __restrict__ w_fc,
    const float* __restrict__ b_fc, float* __restrict__ out)
{
    __shared__ __align__(16) _Float16 hls[4][2 * HSTR];   // per-wave h (single buffer)
    __shared__ __align__(16) _Float16 xls[8][XSTRIDE];
    __shared__ __align__(16) float    ols[8][OSTRIDE];

    const int tid  = threadIdx.x;
    const int w    = tid >> 6;        // wave 0..3 (independent)
    const int lane = tid & 63;
    const int q    = lane >> 4;       // k-quad / D row-group
    const int c    = lane & 15;       // tile column
    const int up   = q & 1;           // act unit-group parity
    const int mb   = q >> 1;          // owned batch within wave (0/1)
    const int bw   = blockIdx.x * 8 + 2 * w;   // first global batch of wave

    // ---- stage x: per-wave (2 rows), coalesced float4 reads ----
    for (int i = lane; i < 256; i += 64) {
        int r = i >> 7, t4 = i & 127;
        float4 v = *(const float4*)(x + (size_t)(bw + r) * T_STEPS + t4 * 4);
        half4v hv;
        hv[0] = (_Float16)v.x; hv[1] = (_Float16)v.y;
        hv[2] = (_Float16)v.z; hv[3] = (_Float16)v.w;
        *(half4v*)(&xls[2 * w + r][t4 * 4]) = hv;
    }
    _Float16* hbw = &hls[w][0];
    for (int i = lane; i < 80; i += 64) ((int*)hbw)[i] = 0;   // h(-1)=0 (320 B)

    // ---- B fragments: tile (n=class, u=unit-group), prescaled ----
    // lane (q,c): B[k=32kk+8q+jj][col c] = sK[n]*w_hh[g][k], g = 64n+16u+c
    const float sK[4] = { -K1, -K1, K2, -K1 };
    half8v bfrag[4][4][2];
    float biasA[4], wihA[4], biasB[4], wihB[4];
#pragma unroll
    for (int n = 0; n < 4; ++n) {
#pragma unroll
        for (int u = 0; u < 4; ++u) {
            int g = 64 * n + 16 * u + c;
#pragma unroll
            for (int kk = 0; kk < 2; ++kk) {
                const float* wp = w_hh + g * 64 + 32 * kk + 8 * q;
                float4 lo  = *(const float4*)(wp);
                float4 hi4 = *(const float4*)(wp + 4);
                half8v f;
                f[0] = (_Float16)(lo.x  * sK[n]); f[1] = (_Float16)(lo.y  * sK[n]);
                f[2] = (_Float16)(lo.z  * sK[n]); f[3] = (_Float16)(lo.w  * sK[n]);
                f[4] = (_Float16)(hi4.x * sK[n]); f[5] = (_Float16)(hi4.y * sK[n]);
                f[6] = (_Float16)(hi4.z * sK[n]); f[7] = (_Float16)(hi4.w * sK[n]);
                bfrag[n][u][kk] = f;
            }
        }
        int gA = 64 * n + 16 * up + c;          // chainA gate, chainB = gA+32
        biasA[n] = (b_ih[gA] + b_hh[gA]) * sK[n];
        wihA[n]  = w_ih[gA] * sK[n];
        biasB[n] = (b_ih[gA + 32] + b_hh[gA + 32]) * sK[n];
        wihB[n]  = w_ih[gA + 32] * sK[n];
    }

    float wfc0[8], wfc1[8];
#pragma unroll
    for (int j = 0; j < 8; ++j) { wfc0[j] = w_fc[8 * q + j]; wfc1[j] = w_fc[32 + 8 * q + j]; }
    const float bfc = b_fc[0];

    float czA = 0.f, czB = 0.f;
    // chainB(-1) inputs chosen so it computes h=0 and leaves czB=0:
    // v0,v1,v3 = +100 (sig->0), v2 = 0 (tanh->0)
    float vB0 = 100.f, vB1 = 100.f, vB2 = 0.f, vB3 = 100.f;
    const f32x4 zeroq = {0.f, 0.f, 0.f, 0.f};

    LGKM0;   // staging + h-zero visible to all lanes of this wave
    const _Float16* hp = hbw + (c >> 3) * HSTR + 8 * q;
    half8v a0 = *(const half8v*)(hp);        // h(t-1), k 0..31  (zeros now)
    half8v a1 = *(const half8v*)(hp + 32);   // h(t-1), k 32..63 (re-read each step)

    f32x4 acc[4][4];

    for (int tq = 0; tq < 128; ++tq) {
        half4v xh = *(const half4v*)(&xls[2 * w + mb][tq * 4]);
#pragma unroll
        for (int dt = 0; dt < 4; ++dt) {
            const int t  = tq * 4 + dt;
            const float xv = (float)xh[dt];

            // ========== PHASE A: 16 a0-MFMAs ; chainB(t-1) in the gaps ==========
            acc[0][0] = MFMA16(a0, bfrag[0][0][0], zeroq);
            acc[1][0] = MFMA16(a0, bfrag[1][0][0], zeroq);
            float bA = ex2(vB0), bB = ex2(vB2), bF = ex2(vB1), bO = ex2(vB3);
            SGB(8, 2); SGB(2, 4);
            acc[2][0] = MFMA16(a0, bfrag[2][0][0], zeroq);
            acc[3][0] = MFMA16(a0, bfrag[3][0][0], zeroq);
            float bR  = rcp_fast((1.f + bA) * (1.f + bB));
            float bpg = fmaf(bB, K2, -K2);
            float brf = rcp_fast(1.f + bF);
            SGB(8, 2); SGB(2, 6);
            acc[0][1] = MFMA16(a0, bfrag[0][1][0], zeroq);
            acc[1][1] = MFMA16(a0, bfrag[1][1][0], zeroq);
            czB = fmaf(czB, brf, bpg * bR);
            float bcc = fminf(fmaxf(czB, -CZCL), CZCL);
            float bC  = ex2(bcc);
            SGB(8, 2); SGB(2, 5);
            acc[2][1] = MFMA16(a0, bfrag[2][1][0], zeroq);
            acc[3][1] = MFMA16(a0, bfrag[3][1][0], zeroq);
            float bh = (bC - 1.f) * rcp_fast((1.f + bO) * (1.f + bC));
            hbw[mb * HSTR + 32 + 16 * up + c] = (_Float16)bh;   // h(t-1) groups 2/3
            SGB(8, 2); SGB(2, 6);
            LGKM0;
            a1 = *(const half8v*)(hp + 32);     // h(t-1) k 32..63 (just completed)
            acc[0][2] = MFMA16(a0, bfrag[0][2][0], zeroq);
            acc[1][2] = MFMA16(a0, bfrag[1][2][0], zeroq);
            acc[2][2] = MFMA16(a0, bfrag[2][2][0], zeroq);
            acc[3][2] = MFMA16(a0, bfrag[3][2][0], zeroq);
            acc[0][3] = MFMA16(a0, bfrag[0][3][0], zeroq);
            acc[1][3] = MFMA16(a0, bfrag[1][3][0], zeroq);
            acc[2][3] = MFMA16(a0, bfrag[2][3][0], zeroq);
            acc[3][3] = MFMA16(a0, bfrag[3][3][0], zeroq);
            SGB(8, 8);

            // ========== PHASE B: 16 a1-MFMAs ; chainA(t) in the gaps ==========
            acc[0][0] = MFMA16(a1, bfrag[0][0][1], acc[0][0]);
            acc[1][0] = MFMA16(a1, bfrag[1][0][1], acc[1][0]);
            acc[2][0] = MFMA16(a1, bfrag[2][0][1], acc[2][0]);
            acc[3][0] = MFMA16(a1, bfrag[3][0][1], acc[3][0]);
            acc[0][1] = MFMA16(a1, bfrag[0][1][1], acc[0][1]);
            acc[1][1] = MFMA16(a1, bfrag[1][1][1], acc[1][1]);
            acc[2][1] = MFMA16(a1, bfrag[2][1][1], acc[2][1]);
            acc[3][1] = MFMA16(a1, bfrag[3][1][1], acc[3][1]);
            SGB(8, 8);
            float av0 = (up ? acc[0][1][0] : acc[0][0][0]) + fmaf(xv, wihA[0], biasA[0]);
            float av1 = (up ? acc[1][1][0] : acc[1][0][0]) + fmaf(xv, wihA[1], biasA[1]);
            float av2 = (up ? acc[2][1][0] : acc[2][0][0]) + fmaf(xv, wihA[2], biasA[2]);
            float av3 = (up ? acc[3][1][0] : acc[3][0][0]) + fmaf(xv, wihA[3], biasA[3]);
            float aA = ex2(av0), aB2 = ex2(av2), aF = ex2(av1), aO = ex2(av3);
            SGB(2, 16);
            acc[0][2] = MFMA16(a1, bfrag[0][2][1], acc[0][2]);
            acc[1][2] = MFMA16(a1, bfrag[1][2][1], acc[1][2]);
            float aR  = rcp_fast((1.f + aA) * (1.f + aB2));
            float apg = fmaf(aB2, K2, -K2);
            float arf = rcp_fast(1.f + aF);
            SGB(8, 2); SGB(2, 6);
            acc[2][2] = MFMA16(a1, bfrag[2][2][1], acc[2][2]);
            acc[3][2] = MFMA16(a1, bfrag[3][2][1], acc[3][2]);
            czA = fmaf(czA, arf, apg * aR);
            float acl = fminf(fmaxf(czA, -CZCL), CZCL);
            float aC  = ex2(acl);
            SGB(8, 2); SGB(2, 5);
            acc[0][3] = MFMA16(a1, bfrag[0][3][1], acc[0][3]);
            acc[1][3] = MFMA16(a1, bfrag[1][3][1], acc[1][3]);
            float ah = (aC - 1.f) * rcp_fast((1.f + aO) * (1.f + aC));
            hbw[mb * HSTR + 16 * up + c] = (_Float16)ah;        // h(t) groups 0/1
            SGB(8, 2); SGB(2, 6);
            LGKM0;
            half8v a0n = *(const half8v*)(hp);   // h(t) k 0..31, latency hidden below
            acc[2][3] = MFMA16(a1, bfrag[2][3][1], acc[2][3]);
            acc[3][3] = MFMA16(a1, bfrag[3][3][1], acc[3][3]);
            SGB(8, 2);

            // fc-dot -> out col t-1 (h(t-1) = {a0, a1}); hides a0n latency
            float s = 0.f;
#pragma unroll
            for (int j = 0; j < 8; ++j) s = fmaf((float)a0[j], wfc0[j], s);
#pragma unroll
            for (int j = 0; j < 8; ++j) s = fmaf((float)a1[j], wfc1[j], s);
            s += __shfl_xor(s, 16);
            s += __shfl_xor(s, 32);
            if (t && (lane == 0 || lane == 8))
                ols[2 * w + (lane >> 3)][t - 1] = s + bfc;

            // vB for chainB(t), consumed in next step's phase A (x = x(t))
            vB0 = (up ? acc[0][3][0] : acc[0][2][0]) + fmaf(xv, wihB[0], biasB[0]);
            vB1 = (up ? acc[1][3][0] : acc[1][2][0]) + fmaf(xv, wihB[1], biasB[1]);
            vB2 = (up ? acc[2][3][0] : acc[2][2][0]) + fmaf(xv, wihB[2], biasB[2]);
            vB3 = (up ? acc[3][3][0] : acc[3][2][0]) + fmaf(xv, wihB[3], biasB[3]);

            a0 = a0n;
        }
    }

    // ---- epilogue: chainB(511), then output col 511 ----
    {
        float bA = ex2(vB0), bB = ex2(vB2), bF = ex2(vB1), bO = ex2(vB3);
        float bR  = rcp_fast((1.f + bA) * (1.f + bB));
        float bpg = fmaf(bB, K2, -K2);
        float brf = rcp_fast(1.f + bF);
        czB = fmaf(czB, brf, bpg * bR);
        float bcc = fminf(fmaxf(czB, -CZCL), CZCL);
        float bC  = ex2(bcc);
        float bh = (bC - 1.f) * rcp_fast((1.f + bO) * (1.f + bC));
        hbw[mb * HSTR + 32 + 16 * up + c] = (_Float16)bh;
        LGKM0;
        a1 = *(const half8v*)(hp + 32);
        float s = 0.f;
#pragma unroll
        for (int j = 0; j < 8; ++j) s = fmaf((float)a0[j], wfc0[j], s);
#pragma unroll
        for (int j = 0; j < 8; ++j) s = fmaf((float)a1[j], wfc1[j], s);
        s += __shfl_xor(s, 16);
        s += __shfl_xor(s, 32);
        if (lane == 0 || lane == 8)
            ols[2 * w + (lane >> 3)][T_STEPS - 1] = s + bfc;
    }
    LGKM0;

    // ---- bulk store: per-wave rows, coalesced ----
    for (int i = lane; i < 2 * T_STEPS; i += 64) {
        int r = i >> 9, tt = i & (T_STEPS - 1);
        out[(size_t)(bw + r) * T_STEPS + tt] = ols[2 * w + r][tt];
    }
}

extern "C" void kernel_launch(void* const* d_in, const int* in_sizes, int n_in,
                              void* d_out, int out_size, void* d_ws, size_t ws_size,
                              hipStream_t stream) {
    const float* x    = (const float*)d_in[0];
    const float* w_ih = (const float*)d_in[1];
    const float* w_hh = (const float*)d_in[2];
    const float* b_ih = (const float*)d_in[3];
    const float* b_hh = (const float*)d_in[4];
    const float* w_fc = (const float*)d_in[5];
    const float* b_fc = (const float*)d_in[6];
    float* out = (float*)d_out;
    hipLaunchKernelGGL(lstm_kernel, dim3(256), dim3(256), 0, stream,
                       x, w_ih, w_hh, b_ih, b_hh, w_fc, b_fc, out);
}

// Round 7
// 255.123 us; speedup vs baseline: 1.4752x; 1.4752x over previous
//
#include <hip/hip_runtime.h>

#define T_STEPS 512
#define HSTR 80        // _Float16 per h batch-row (160 B)
#define XSTRIDE 520    // _Float16 per x-row
#define OSTRIDE 513    // floats per out-row
#define NB 4           // batches per block; 512 blocks = 2 blocks/CU

typedef _Float16 half8v __attribute__((ext_vector_type(8)));
typedef _Float16 half4v __attribute__((ext_vector_type(4)));
typedef float f32x4 __attribute__((ext_vector_type(4)));

#define K1 1.442695041f    // log2(e)
#define K2 2.885390082f    // 2*log2(e)
#define CZCL 43.28085123f  // 15*K2, clamp in cz = cs*K2 domain

__device__ __forceinline__ float ex2(float x) {
#if __has_builtin(__builtin_amdgcn_exp2f)
    return __builtin_amdgcn_exp2f(x);
#else
    return exp2f(x);
#endif
}
__device__ __forceinline__ float rcp_fast(float x) {
#if __has_builtin(__builtin_amdgcn_rcpf)
    return __builtin_amdgcn_rcpf(x);
#else
    return 1.0f / x;
#endif
}

// partial fc-dot over this lane's A-frag slice (f16), reduced over the 4 k-quads
__device__ __forceinline__ float out_dot(half8v a0, half8v a1,
                                         const float* wfc0, const float* wfc1) {
    float s = 0.f;
#pragma unroll
    for (int j = 0; j < 8; ++j) s = fmaf((float)a0[j], wfc0[j], s);
#pragma unroll
    for (int j = 0; j < 8; ++j) s = fmaf((float)a1[j], wfc1[j], s);
    s += __shfl_xor(s, 16);
    s += __shfl_xor(s, 32);
    return s;   // full 64-dot for batch (c>>2), on all lanes
}

// R17 = R15 champion + two dependency cuts:
//  (1) MFMA pair UN-chained: acc0=MFMA(a0,B0,0), acc1=MFMA(a1,B1,0)
//      independent, elem-0 summed in VALU -> removes one MFMA latency
//      (~40 cyc) from the serial recurrence.
//  (2) act tail: h = Ro - 2Ro*rcp(1+C), with Ro=rcp(1+ex2(v3)) and -2Ro
//      computed OFF the cz critical path -> post-C depth add->rcp->fma.
// Topology identical to R11/R15: NB=4, 4 waves, 2 blocks/CU, A rows m ->
// h[m>>2], one act chain per lane (batch q, unit 16w+c), 1 barrier/step,
// fc-dot in the dt==0 ds_read latency shadow, cz = cs*K2 domain.
__global__ __launch_bounds__(256, 2) void lstm_kernel(
    const float* __restrict__ x, const float* __restrict__ w_ih,
    const float* __restrict__ w_hh, const float* __restrict__ b_ih,
    const float* __restrict__ b_hh, const float* __restrict__ w_fc,
    const float* __restrict__ b_fc, float* __restrict__ out)
{
    __shared__ __align__(16) _Float16 hbuf[2][NB * HSTR];   // 1.3 KB
    __shared__ __align__(16) _Float16 xls[NB * XSTRIDE];    // 4.2 KB
    __shared__ __align__(16) float ols[NB * OSTRIDE];       // 8.2 KB

    const int tid  = threadIdx.x;
    const int w    = tid >> 6;        // wave 0..3
    const int lane = tid & 63;
    const int q    = lane >> 4;       // quad (A k-group / D row-group)
    const int c    = lane & 15;       // unit-in-tile / A-row
    const int b0   = blockIdx.x * NB;

    // ---- stage x: global -> LDS (f16), coalesced float4 reads ----
    for (int i = tid; i < NB * 128; i += 256) {      // 4 rows x 128 float4
        int b  = i >> 7;
        int t4 = i & 127;
        float4 v = *(const float4*)(x + (size_t)(b0 + b) * T_STEPS + t4 * 4);
        half4v hv;
        hv[0] = (_Float16)v.x; hv[1] = (_Float16)v.y;
        hv[2] = (_Float16)v.z; hv[3] = (_Float16)v.w;
        *(half4v*)(&xls[b * XSTRIDE + t4 * 4]) = hv;
    }
    // zero both h buffers (h_{-1} = 0)
    for (int i = tid; i < 2 * NB * HSTR / 2; i += 256) ((int*)hbuf)[i] = 0;

    // ---- B fragments (prescaled weights): tile n = gate class ----
    // lane (q,c) holds B[k=32kk+8q+jj][col c] = sK[n]*w_hh[g][k], g = 64n+16w+c
    const float sK[4] = { -K1, -K1, K2, -K1 };   // i,f sig; g tanh; o sig
    half8v bfrag[4][2];
    float biasS[4], wihS[4];
#pragma unroll
    for (int n = 0; n < 4; ++n) {
        int g = 64 * n + 16 * w + c;
        biasS[n] = (b_ih[g] + b_hh[g]) * sK[n];
        wihS[n]  = w_ih[g] * sK[n];
#pragma unroll
        for (int kk = 0; kk < 2; ++kk) {
            const float* wp = w_hh + g * 64 + 32 * kk + 8 * q;
            float4 lo  = *(const float4*)(wp);
            float4 hi4 = *(const float4*)(wp + 4);
            half8v f;
            f[0] = (_Float16)(lo.x  * sK[n]); f[1] = (_Float16)(lo.y  * sK[n]);
            f[2] = (_Float16)(lo.z  * sK[n]); f[3] = (_Float16)(lo.w  * sK[n]);
            f[4] = (_Float16)(hi4.x * sK[n]); f[5] = (_Float16)(hi4.y * sK[n]);
            f[6] = (_Float16)(hi4.z * sK[n]); f[7] = (_Float16)(hi4.w * sK[n]);
            bfrag[n][kk] = f;
        }
    }

    // fc weights aligned to this lane's A-frag k-slice
    float wfc0[8], wfc1[8];
#pragma unroll
    for (int j = 0; j < 8; ++j) { wfc0[j] = w_fc[8 * q + j]; wfc1[j] = w_fc[32 + 8 * q + j]; }
    const float bfc = b_fc[0];

    float cz = 0.f;               // cell state * K2 (batch q, unit 16w+c)
    const f32x4 zeroq = {0.f, 0.f, 0.f, 0.f};

    __syncthreads();

    half8v sa0 = {}, sa1 = {};  // saved A-frags for rotated fc-dot

    for (int tq = 0; tq < 128; ++tq) {
        // x for this lane's OWN batch (q), 4 steps (broadcast read)
        half4v xh = *(const half4v*)(&xls[q * XSTRIDE + tq * 4]);

#pragma unroll
        for (int dt = 0; dt < 4; ++dt) {
            const int t  = tq * 4 + dt;
            const int rb = t & 1;

            // A-frags: A[m][k] = h[m>>2][k]; lane row m=c -> LDS row c>>2
            const _Float16* hp = hbuf[rb] + (c >> 2) * HSTR + 8 * q;
            half8v a0 = *(const half8v*)(hp);        // k = 8q+j
            half8v a1 = *(const half8v*)(hp + 32);   // k = 32+8q+j

            if (dt == 0) {
                // pending fc-dot from previous tq, issued in the ds_read
                // latency shadow (independent of a0/a1). Saved frag was the
                // A of step stp = 4(tq-1)+w = h(stp-1) -> column stp-1.
                int stp = 4 * tq - 4 + w;
                if (tq > 0 && stp > 0) {
                    float s = out_dot(sa0, sa1, wfc0, wfc1);
                    if (lane < 16 && (lane & 3) == 0)
                        ols[(lane >> 2) * OSTRIDE + (stp - 1)] = s + bfc;
                }
            }

            if (dt == w) { sa0 = a0; sa1 = a1; }     // rotate fc-dot ownership

            // scalar x*wih+bias for the owned batch (off critical path)
            const float xv = (float)xh[dt];
            float xb[4];
#pragma unroll
            for (int n = 0; n < 4; ++n) xb[n] = fmaf(xv, wihS[n], biasS[n]);

            // gates: 4 class tiles, K=64 via two INDEPENDENT MFMAs (no
            // C-chain); elem-0 partials summed in VALU
            f32x4 acc0[4], acc1[4];
#pragma unroll
            for (int n = 0; n < 4; ++n)
                acc0[n] = __builtin_amdgcn_mfma_f32_16x16x32_f16(a0, bfrag[n][0], zeroq, 0, 0, 0);
#pragma unroll
            for (int n = 0; n < 4; ++n)
                acc1[n] = __builtin_amdgcn_mfma_f32_16x16x32_f16(a1, bfrag[n][1], zeroq, 0, 0, 0);

            // rows 4q..4q+3 are all batch q -> elem 0 only; acc0 finishes
            // first, so fold xb into it while acc1 completes
            float v0 = (acc0[0][0] + xb[0]) + acc1[0][0];
            float v1 = (acc0[1][0] + xb[1]) + acc1[1][0];
            float v2 = (acc0[2][0] + xb[2]) + acc1[2][0];
            float v3 = (acc0[3][0] + xb[3]) + acc1[3][0];

            // fused activations, cz = cs*K2 domain; lane owns (q, 16w+c)
            {
                float A   = ex2(v0);                    // e^{-i}
                float Bt  = ex2(v2);                    // e^{2g}
                float Ao  = ex2(v3);                    // e^{-o}  (parallel)
                float rf  = rcp_fast(1.0f + ex2(v1));   // sig(f)  (parallel)
                float R   = rcp_fast((1.0f + A) * (1.0f + Bt));
                float igk = fmaf(Bt, K2, -K2) * R;      // i*g*K2
                cz = fmaf(cz, rf, igk);
                float Ro  = rcp_fast(1.0f + Ao);        // off cz path
                float m2R = -2.0f * Ro;                 // off cz path
                float cc  = fminf(fmaxf(cz, -CZCL), CZCL);
                float C   = ex2(cc);                    // e^{2c}
                float h   = fmaf(m2R, rcp_fast(1.0f + C), Ro);
                hbuf[rb ^ 1][q * HSTR + 16 * w + c] = (_Float16)h;
            }
            __syncthreads();
        }
    }

    // epilogue pending fc-dot: saved frag from tq=127 -> st = 508+w,
    // column 507+w (covers 507..510)
    {
        float s = out_dot(sa0, sa1, wfc0, wfc1);
        if (lane < 16 && (lane & 3) == 0)
            ols[(lane >> 2) * OSTRIDE + (507 + w)] = s + bfc;
    }

    // final output column: h_511 lives in hbuf[0]
    if (w == 3) {
        const _Float16* hp = hbuf[0] + (c >> 2) * HSTR + 8 * q;
        half8v a0 = *(const half8v*)(hp);
        half8v a1 = *(const half8v*)(hp + 32);
        float s = out_dot(a0, a1, wfc0, wfc1);
        if (lane < 16 && (lane & 3) == 0)
            ols[(lane >> 2) * OSTRIDE + (T_STEPS - 1)] = s + bfc;
    }
    __syncthreads();

    // bulk store: LDS out -> global, coalesced
    for (int i = tid; i < NB * T_STEPS; i += 256) {
        int b = i >> 9;
        int t = i & (T_STEPS - 1);
        out[(size_t)(b0 + b) * T_STEPS + t] = ols[b * OSTRIDE + t];
    }
}

extern "C" void kernel_launch(void* const* d_in, const int* in_sizes, int n_in,
                              void* d_out, int out_size, void* d_ws, size_t ws_size,
                              hipStream_t stream) {
    const float* x    = (const float*)d_in[0];
    const float* w_ih = (const float*)d_in[1];
    const float* w_hh = (const float*)d_in[2];
    const float* b_ih = (const float*)d_in[3];
    const float* b_hh = (const float*)d_in[4];
    const float* w_fc = (const float*)d_in[5];
    const float* b_fc = (const float*)d_in[6];
    float* out = (float*)d_out;
    hipLaunchKernelGGL(lstm_kernel, dim3(2048 / NB), dim3(256), 0, stream,
                       x, w_ih, w_hh, b_ih, b_hh, w_fc, b_fc, out);
}